// Round 1
// baseline (140.490 us; speedup 1.0000x reference)
//
#include <hip/hip_runtime.h>

#define THRESH 1.0f

// Kernel 1: mode_scores = softmax(x @ W^T + b) per batch row.
// One block (256 threads = 4 waves) per row b. M == D == 256 assumed.
__global__ __launch_bounds__(256) void scores_kernel(
    const float* __restrict__ x, const float* __restrict__ W,
    const float* __restrict__ bias, float* __restrict__ scores,
    int D, int M)
{
    const int b = blockIdx.x;
    __shared__ __align__(16) float x_lds[256];
    __shared__ float logits[256];
    __shared__ float wred[4];

    const int tid  = threadIdx.x;
    const int wave = tid >> 6;
    const int lane = tid & 63;

    x_lds[tid] = x[(size_t)b * D + tid];
    __syncthreads();

    // Each wave computes 64 logits; per logit: coalesced float4 row of W,
    // 4-elem partial dot, 64-lane butterfly reduce.
    const float4* W4 = reinterpret_cast<const float4*>(W);
    const float4  xv = reinterpret_cast<const float4*>(x_lds)[lane];
    for (int i = 0; i < 64; ++i) {
        const int m = wave * 64 + i;
        const float4 wv = W4[(size_t)m * 64 + lane];
        float p = wv.x * xv.x + wv.y * xv.y + wv.z * xv.z + wv.w * xv.w;
        #pragma unroll
        for (int off = 32; off; off >>= 1) p += __shfl_xor(p, off, 64);
        if (lane == 0) logits[m] = p + bias[m];
    }
    __syncthreads();

    // Block softmax over 256 logits (one per thread).
    float l = logits[tid];
    float mx = l;
    #pragma unroll
    for (int off = 32; off; off >>= 1) mx = fmaxf(mx, __shfl_xor(mx, off, 64));
    if (lane == 0) wred[wave] = mx;
    __syncthreads();
    mx = fmaxf(fmaxf(wred[0], wred[1]), fmaxf(wred[2], wred[3]));
    __syncthreads();               // wred reuse guard

    const float e = expf(l - mx);
    float s = e;
    #pragma unroll
    for (int off = 32; off; off >>= 1) s += __shfl_xor(s, off, 64);
    if (lane == 0) wred[wave] = s;
    __syncthreads();
    const float tot = wred[0] + wred[1] + wred[2] + wred[3];

    scores[(size_t)b * M + tid] = e / tot;
}

// Kernel 2: per (b,d) position (float4-vectorized), loop over modes m:
//   reset   = (mem > 1) ? 1 : 0           (on incoming mem_states)
//   mem_new = m*mem + x - reset           (exact-IEEE, no FMA contraction)
//   spike   = (mem_new - 1 > 0) ? 1 : 0   -> count
//   mixed   = scores_flat[pos] * count    (D == M flat-index coincidence)
__global__ __launch_bounds__(256) void neuron_kernel(
    const float* __restrict__ x, const float* __restrict__ mem,
    const float* __restrict__ scores, float* __restrict__ mixed,
    float* __restrict__ mem_new, int M, int plane4)
{
    const int idx = blockIdx.x * 256 + threadIdx.x;
    if (idx >= plane4) return;

    const float4* x4   = reinterpret_cast<const float4*>(x);
    const float4* mem4 = reinterpret_cast<const float4*>(mem);
    const float4* sc4  = reinterpret_cast<const float4*>(scores);
    float4* out4       = reinterpret_cast<float4*>(mem_new);
    float4* mix4       = reinterpret_cast<float4*>(mixed);

    const float4 xv = x4[idx];
    float cx = 0.f, cy = 0.f, cz = 0.f, cw = 0.f;

    #pragma unroll 4
    for (int m = 0; m < M; ++m) {
        const float bm = (float)m;
        const size_t off = (size_t)m * plane4 + idx;
        const float4 mv = mem4[off];

        float4 nv;
        nv.x = __fsub_rn(__fadd_rn(__fmul_rn(bm, mv.x), xv.x),
                         (mv.x - THRESH > 0.f) ? THRESH : 0.f);
        nv.y = __fsub_rn(__fadd_rn(__fmul_rn(bm, mv.y), xv.y),
                         (mv.y - THRESH > 0.f) ? THRESH : 0.f);
        nv.z = __fsub_rn(__fadd_rn(__fmul_rn(bm, mv.z), xv.z),
                         (mv.z - THRESH > 0.f) ? THRESH : 0.f);
        nv.w = __fsub_rn(__fadd_rn(__fmul_rn(bm, mv.w), xv.w),
                         (mv.w - THRESH > 0.f) ? THRESH : 0.f);

        out4[off] = nv;

        cx += (nv.x - THRESH > 0.f) ? 1.f : 0.f;
        cy += (nv.y - THRESH > 0.f) ? 1.f : 0.f;
        cz += (nv.z - THRESH > 0.f) ? 1.f : 0.f;
        cw += (nv.w - THRESH > 0.f) ? 1.f : 0.f;
    }

    const float4 sc = sc4[idx];
    float4 mx;
    mx.x = sc.x * cx; mx.y = sc.y * cy; mx.z = sc.z * cz; mx.w = sc.w * cw;
    mix4[idx] = mx;
}

extern "C" void kernel_launch(void* const* d_in, const int* in_sizes, int n_in,
                              void* d_out, int out_size, void* d_ws, size_t ws_size,
                              hipStream_t stream) {
    const float* x    = (const float*)d_in[0];
    const float* mem  = (const float*)d_in[1];
    const float* W    = (const float*)d_in[2];
    const float* bias = (const float*)d_in[3];

    const int M = in_sizes[3];             // 256
    const int D = in_sizes[2] / M;         // 256
    const int B = in_sizes[0] / D;         // 1024
    const int plane = B * D;               // 262144

    float* out_mixed  = (float*)d_out;                       // [B*D]
    float* out_mem    = out_mixed + plane;                   // [M*B*D]
    float* out_scores = out_mem + (size_t)M * plane;         // [B*M]

    scores_kernel<<<B, 256, 0, stream>>>(x, W, bias, out_scores, D, M);

    const int plane4 = plane / 4;          // 65536
    neuron_kernel<<<(plane4 + 255) / 256, 256, 0, stream>>>(
        x, mem, out_scores, out_mixed, out_mem, M, plane4);
}

// Round 3
// 116.500 us; speedup vs baseline: 1.2059x; 1.2059x over previous
//
#include <hip/hip_runtime.h>

#define THRESH 1.0f

typedef float fvec4 __attribute__((ext_vector_type(4)));

// ---------- W transpose: Wt[k][m] = W[m][k] (into d_ws) ----------
__global__ __launch_bounds__(256) void transpose_kernel(
    const float* __restrict__ W, float* __restrict__ Wt, int M, int D)
{
    __shared__ float tile[32][33];
    const int tilesK = D / 32;
    const int bx = blockIdx.x % tilesK;   // k tile
    const int by = blockIdx.x / tilesK;   // m tile
    const int lx = threadIdx.x & 31;
    const int ly = threadIdx.x >> 5;      // 0..7
    #pragma unroll
    for (int j = 0; j < 4; ++j)
        tile[ly + j * 8][lx] = W[(size_t)(by * 32 + ly + j * 8) * D + bx * 32 + lx];
    __syncthreads();
    #pragma unroll
    for (int j = 0; j < 4; ++j)
        Wt[(size_t)(bx * 32 + ly + j * 8) * M + by * 32 + lx] = tile[lx][ly + j * 8];
}

// ---------- scores = softmax(x @ W^T + b), via Wt; one block per row ----------
// Thread tid owns logit m=tid: coalesced 4B loads of Wt[k][tid], x broadcast from LDS.
__global__ __launch_bounds__(256) void scores_kernel2(
    const float* __restrict__ Wt, const float* __restrict__ x,
    const float* __restrict__ bias, float* __restrict__ scores,
    int D, int M)
{
    const int b   = blockIdx.x;
    const int tid = threadIdx.x;
    const int wave = tid >> 6;
    const int lane = tid & 63;
    __shared__ __align__(16) float x_lds[256];
    __shared__ float wred[4];

    x_lds[tid] = x[(size_t)b * D + tid];
    __syncthreads();

    float a0 = 0.f, a1 = 0.f, a2 = 0.f, a3 = 0.f;
    const float4* x4l = reinterpret_cast<const float4*>(x_lds);
    #pragma unroll 4
    for (int k = 0; k < D; k += 4) {
        const float4 xk = x4l[k >> 2];               // LDS broadcast
        a0 = fmaf(Wt[(size_t)(k + 0) * M + tid], xk.x, a0);
        a1 = fmaf(Wt[(size_t)(k + 1) * M + tid], xk.y, a1);
        a2 = fmaf(Wt[(size_t)(k + 2) * M + tid], xk.z, a2);
        a3 = fmaf(Wt[(size_t)(k + 3) * M + tid], xk.w, a3);
    }
    const float l = (a0 + a1) + (a2 + a3) + bias[tid];

    // block softmax over 256 logits (one per thread)
    float mx = l;
    #pragma unroll
    for (int off = 32; off; off >>= 1) mx = fmaxf(mx, __shfl_xor(mx, off, 64));
    if (lane == 0) wred[wave] = mx;
    __syncthreads();
    mx = fmaxf(fmaxf(wred[0], wred[1]), fmaxf(wred[2], wred[3]));
    __syncthreads();

    const float e = expf(l - mx);
    float s = e;
    #pragma unroll
    for (int off = 32; off; off >>= 1) s += __shfl_xor(s, off, 64);
    if (lane == 0) wred[wave] = s;
    __syncthreads();
    const float tot = wred[0] + wred[1] + wred[2] + wred[3];

    scores[(size_t)b * M + tid] = e / tot;
}

// ---------- neuron: mem_new + per-chunk spike counts ----------
// Grid = nPosBlocks * nchunk blocks; block handles 256 float4 positions for
// one m-chunk of size mchunk. Counts (exact small ints) -> ws, no atomics.
__global__ __launch_bounds__(256) void neuron_count_kernel(
    const float* __restrict__ x, const float* __restrict__ mem,
    float* __restrict__ mem_new, float* __restrict__ counts,
    int plane4, int nPosBlocks, int mchunk)
{
    const int posb = blockIdx.x % nPosBlocks;
    const int mc   = blockIdx.x / nPosBlocks;
    const int idx  = posb * 256 + threadIdx.x;
    if (idx >= plane4) return;

    const fvec4* x4   = reinterpret_cast<const fvec4*>(x);
    const fvec4* mem4 = reinterpret_cast<const fvec4*>(mem);
    fvec4* out4       = reinterpret_cast<fvec4*>(mem_new);

    const fvec4 xv = x4[idx];
    const int m0 = mc * mchunk;
    float cx = 0.f, cy = 0.f, cz = 0.f, cw = 0.f;

    #pragma unroll 4
    for (int mm = 0; mm < mchunk; ++mm) {
        const int m = m0 + mm;
        const float bm = (float)m;
        const size_t off = (size_t)m * plane4 + idx;
        const fvec4 mv = __builtin_nontemporal_load(&mem4[off]);

        fvec4 nv;
        nv.x = __fsub_rn(__fadd_rn(__fmul_rn(bm, mv.x), xv.x),
                         (mv.x - THRESH > 0.f) ? THRESH : 0.f);
        nv.y = __fsub_rn(__fadd_rn(__fmul_rn(bm, mv.y), xv.y),
                         (mv.y - THRESH > 0.f) ? THRESH : 0.f);
        nv.z = __fsub_rn(__fadd_rn(__fmul_rn(bm, mv.z), xv.z),
                         (mv.z - THRESH > 0.f) ? THRESH : 0.f);
        nv.w = __fsub_rn(__fadd_rn(__fmul_rn(bm, mv.w), xv.w),
                         (mv.w - THRESH > 0.f) ? THRESH : 0.f);

        __builtin_nontemporal_store(nv, &out4[off]);

        cx += (nv.x - THRESH > 0.f) ? 1.f : 0.f;
        cy += (nv.y - THRESH > 0.f) ? 1.f : 0.f;
        cz += (nv.z - THRESH > 0.f) ? 1.f : 0.f;
        cw += (nv.w - THRESH > 0.f) ? 1.f : 0.f;
    }
    fvec4 cv; cv.x = cx; cv.y = cy; cv.z = cz; cv.w = cw;
    reinterpret_cast<fvec4*>(counts)[(size_t)mc * plane4 + idx] = cv;
}

// ---------- mix: mixed = scores_flat * sum(counts over chunks) ----------
__global__ __launch_bounds__(256) void mix_kernel(
    const float* __restrict__ scores, const float* __restrict__ counts,
    float* __restrict__ mixed, int plane4, int nchunk)
{
    const int idx = blockIdx.x * 256 + threadIdx.x;
    if (idx >= plane4) return;
    const fvec4* c4 = reinterpret_cast<const fvec4*>(counts);
    fvec4 c = c4[idx];
    for (int j = 1; j < nchunk; ++j) {
        const fvec4 cj = c4[(size_t)j * plane4 + idx];
        c.x += cj.x; c.y += cj.y; c.z += cj.z; c.w += cj.w;
    }
    const fvec4 sc = reinterpret_cast<const fvec4*>(scores)[idx];
    fvec4 mx;
    mx.x = sc.x * c.x; mx.y = sc.y * c.y; mx.z = sc.z * c.z; mx.w = sc.w * c.w;
    reinterpret_cast<fvec4*>(mixed)[idx] = mx;
}

// ---------- fallback kernels (round-1, used if ws too small) ----------
__global__ __launch_bounds__(256) void scores_kernel_fb(
    const float* __restrict__ x, const float* __restrict__ W,
    const float* __restrict__ bias, float* __restrict__ scores,
    int D, int M)
{
    const int b = blockIdx.x;
    __shared__ __align__(16) float x_lds[256];
    __shared__ float logits[256];
    __shared__ float wred[4];
    const int tid  = threadIdx.x;
    const int wave = tid >> 6;
    const int lane = tid & 63;
    x_lds[tid] = x[(size_t)b * D + tid];
    __syncthreads();
    const float4* W4 = reinterpret_cast<const float4*>(W);
    const float4  xv = reinterpret_cast<const float4*>(x_lds)[lane];
    for (int i = 0; i < 64; ++i) {
        const int m = wave * 64 + i;
        const float4 wv = W4[(size_t)m * 64 + lane];
        float p = wv.x * xv.x + wv.y * xv.y + wv.z * xv.z + wv.w * xv.w;
        #pragma unroll
        for (int off = 32; off; off >>= 1) p += __shfl_xor(p, off, 64);
        if (lane == 0) logits[m] = p + bias[m];
    }
    __syncthreads();
    float l = logits[tid];
    float mx = l;
    #pragma unroll
    for (int off = 32; off; off >>= 1) mx = fmaxf(mx, __shfl_xor(mx, off, 64));
    if (lane == 0) wred[wave] = mx;
    __syncthreads();
    mx = fmaxf(fmaxf(wred[0], wred[1]), fmaxf(wred[2], wred[3]));
    __syncthreads();
    const float e = expf(l - mx);
    float s = e;
    #pragma unroll
    for (int off = 32; off; off >>= 1) s += __shfl_xor(s, off, 64);
    if (lane == 0) wred[wave] = s;
    __syncthreads();
    const float tot = wred[0] + wred[1] + wred[2] + wred[3];
    scores[(size_t)b * M + tid] = e / tot;
}

__global__ __launch_bounds__(256) void neuron_kernel_fb(
    const float* __restrict__ x, const float* __restrict__ mem,
    const float* __restrict__ scores, float* __restrict__ mixed,
    float* __restrict__ mem_new, int M, int plane4)
{
    const int idx = blockIdx.x * 256 + threadIdx.x;
    if (idx >= plane4) return;
    const float4* x4   = reinterpret_cast<const float4*>(x);
    const float4* mem4 = reinterpret_cast<const float4*>(mem);
    const float4* sc4  = reinterpret_cast<const float4*>(scores);
    float4* out4       = reinterpret_cast<float4*>(mem_new);
    float4* mix4       = reinterpret_cast<float4*>(mixed);
    const float4 xv = x4[idx];
    float cx = 0.f, cy = 0.f, cz = 0.f, cw = 0.f;
    #pragma unroll 4
    for (int m = 0; m < M; ++m) {
        const float bm = (float)m;
        const size_t off = (size_t)m * plane4 + idx;
        const float4 mv = mem4[off];
        float4 nv;
        nv.x = __fsub_rn(__fadd_rn(__fmul_rn(bm, mv.x), xv.x),
                         (mv.x - THRESH > 0.f) ? THRESH : 0.f);
        nv.y = __fsub_rn(__fadd_rn(__fmul_rn(bm, mv.y), xv.y),
                         (mv.y - THRESH > 0.f) ? THRESH : 0.f);
        nv.z = __fsub_rn(__fadd_rn(__fmul_rn(bm, mv.z), xv.z),
                         (mv.z - THRESH > 0.f) ? THRESH : 0.f);
        nv.w = __fsub_rn(__fadd_rn(__fmul_rn(bm, mv.w), xv.w),
                         (mv.w - THRESH > 0.f) ? THRESH : 0.f);
        out4[off] = nv;
        cx += (nv.x - THRESH > 0.f) ? 1.f : 0.f;
        cy += (nv.y - THRESH > 0.f) ? 1.f : 0.f;
        cz += (nv.z - THRESH > 0.f) ? 1.f : 0.f;
        cw += (nv.w - THRESH > 0.f) ? 1.f : 0.f;
    }
    const float4 sc = sc4[idx];
    float4 mx;
    mx.x = sc.x * cx; mx.y = sc.y * cy; mx.z = sc.z * cz; mx.w = sc.w * cw;
    mix4[idx] = mx;
}

extern "C" void kernel_launch(void* const* d_in, const int* in_sizes, int n_in,
                              void* d_out, int out_size, void* d_ws, size_t ws_size,
                              hipStream_t stream) {
    const float* x    = (const float*)d_in[0];
    const float* mem  = (const float*)d_in[1];
    const float* W    = (const float*)d_in[2];
    const float* bias = (const float*)d_in[3];

    const int M = in_sizes[3];             // 256
    const int D = in_sizes[2] / M;         // 256
    const int B = in_sizes[0] / D;         // 1024
    const int plane  = B * D;              // 262144
    const int plane4 = plane / 4;          // 65536

    float* out_mixed  = (float*)d_out;                       // [B*D]
    float* out_mem    = out_mixed + plane;                   // [M*B*D]
    float* out_scores = out_mem + (size_t)M * plane;         // [B*M]

    const int nchunk = 4;
    const int mchunk = M / nchunk;                           // 64
    const size_t wt_bytes    = (size_t)M * D * sizeof(float);        // 256 KB
    const size_t count_bytes = (size_t)nchunk * plane4 * 16;         // 4 MB

    if (ws_size >= wt_bytes + count_bytes) {
        float* Wt     = (float*)d_ws;
        float* counts = (float*)((char*)d_ws + wt_bytes);

        transpose_kernel<<<(M / 32) * (D / 32), 256, 0, stream>>>(W, Wt, M, D);
        scores_kernel2<<<B, 256, 0, stream>>>(Wt, x, bias, out_scores, D, M);

        const int nPosBlocks = (plane4 + 255) / 256;         // 256
        neuron_count_kernel<<<nPosBlocks * nchunk, 256, 0, stream>>>(
            x, mem, out_mem, counts, plane4, nPosBlocks, mchunk);
        mix_kernel<<<nPosBlocks, 256, 0, stream>>>(
            out_scores, counts, out_mixed, plane4, nchunk);
    } else {
        scores_kernel_fb<<<B, 256, 0, stream>>>(x, W, bias, out_scores, D, M);
        neuron_kernel_fb<<<(plane4 + 255) / 256, 256, 0, stream>>>(
            x, mem, out_scores, out_mixed, out_mem, M, plane4);
    }
}